// Round 3
// baseline (682.496 us; speedup 1.0000x reference)
//
#include <hip/hip_runtime.h>

// Problem constants (fixed shapes from setup_inputs)
constexpr int B  = 4;
constexpr int N  = 16384;   // dense points
constexpr int S  = 4096;    // sparse points
constexpr int CD = 128;     // dense feature channels
constexpr int CS = 256;     // sparse feature channels
constexpr int CO = 128;     // output channels
constexpr int CIN = CD + CS; // 384

// KNN decomposition
constexpr int NC = 8;      // S-chunks
constexpr int CH = S / NC; // 512 sparse points per chunk
constexpr int P  = 2;      // dense points per thread -> 1024 blocks (4/CU)

// Packed key: f64(dist_f32) with sparse index OR'd into low 12 mantissa bits.
// Exact lexicographic (dist, idx) ordering: f32 dists differ by >= 2^-24 rel,
// idx bits perturb <= 2^-40 rel. Ties -> lower idx = jax top_k stability.
__device__ __forceinline__ double pack_key(float dist, unsigned sg) {
  return __longlong_as_double(
      (long long)(__double_as_longlong((double)dist) | (unsigned long long)sg));
}

// Insert x into ascending (k0,k1,k2), dropping the largest. 5 f64 min/max.
__device__ __forceinline__ void insert3(double& k0, double& k1, double& k2,
                                        double x) {
  const double m0 = fmax(k0, x);
  const double m1 = fmax(k1, x);
  k0 = fmin(k0, x);
  k1 = fmin(k1, m0);
  k2 = fmin(k2, m1);
}

// ---------------------------------------------------------------------------
// K1a: per-chunk top-3 as packed f64 keys. Pure min/max dataflow (no cmp /
// cndmask chains), LDS-broadcast sparse coords, 2 points per thread.
// ---------------------------------------------------------------------------
__global__ __launch_bounds__(256) void knn_chunk_kernel(
    const float* __restrict__ dxyz, const float* __restrict__ sxyz,
    double* __restrict__ ckey) {
  __shared__ float4 sp[CH];
  const int b = blockIdx.z;
  const int c = blockIdx.y;
  const int nbase = blockIdx.x * (256 * P);
  const int t = threadIdx.x;

  const float* sb = sxyz + b * 3 * S + c * CH;
  for (int j = t; j < CH; j += 256)
    sp[j] = make_float4(sb[j], sb[S + j], sb[2 * S + j], 0.f);
  __syncthreads();

  float bx[P], by[P], bz[P];
  double k0[P], k1[P], k2[P];
  #pragma unroll
  for (int p = 0; p < P; ++p) {
    const int n = nbase + p * 256 + t;
    bx[p] = dxyz[b * 3 * N + n];
    by[p] = dxyz[b * 3 * N + N + n];
    bz[p] = dxyz[b * 3 * N + 2 * N + n];
    k0[p] = k1[p] = k2[p] = 1e300;
  }

  #pragma unroll 4
  for (int j = 0; j < CH; ++j) {
    const float4 q = sp[j];                 // wave-uniform LDS broadcast
    const unsigned sg = (unsigned)(c * CH + j);  // global sparse index, 12 bits
    #pragma unroll
    for (int p = 0; p < P; ++p) {
      const float ex = bx[p] - q.x, ey = by[p] - q.y, ez = bz[p] - q.z;
      const float dist = fmaf(ex, ex, fmaf(ey, ey, ez * ez));
      insert3(k0[p], k1[p], k2[p], pack_key(dist, sg));
    }
  }

  #pragma unroll
  for (int p = 0; p < P; ++p) {
    const int n = nbase + p * 256 + t;
    const size_t base = (((size_t)c * B + b) * N + n) * 3;
    ckey[base + 0] = k0[p];
    ckey[base + 1] = k1[p];
    ckey[base + 2] = k2[p];
  }
}

// ---------------------------------------------------------------------------
// K1b: merge the NC per-chunk key triples, unpack, emit normalized weights.
// ---------------------------------------------------------------------------
__global__ __launch_bounds__(256) void knn_merge_kernel(
    const double* __restrict__ ckey, float* __restrict__ wgt,
    int* __restrict__ idx) {
  const int gid = blockIdx.x * 256 + threadIdx.x;  // = b*N + n
  double k0 = 1e300, k1 = 1e300, k2 = 1e300;
  #pragma unroll
  for (int c = 0; c < NC; ++c) {
    const size_t base = ((size_t)c * B * N + gid) * 3;
    insert3(k0, k1, k2, ckey[base + 0]);
    insert3(k0, k1, k2, ckey[base + 1]);
    insert3(k0, k1, k2, ckey[base + 2]);
  }
  const long long b0 = __double_as_longlong(k0);
  const long long b1 = __double_as_longlong(k1);
  const long long b2 = __double_as_longlong(k2);
  const float d0 = (float)__longlong_as_double(b0 & ~0xFFFll);
  const float d1 = (float)__longlong_as_double(b1 & ~0xFFFll);
  const float d2 = (float)__longlong_as_double(b2 & ~0xFFFll);
  const float w0 = 1.f / (d0 + 1e-8f);
  const float w1 = 1.f / (d1 + 1e-8f);
  const float w2 = 1.f / (d2 + 1e-8f);
  const float inv = 1.f / (w0 + w1 + w2);
  const size_t base = (size_t)gid * 3;
  wgt[base + 0] = w0 * inv;
  wgt[base + 1] = w1 * inv;
  wgt[base + 2] = w2 * inv;
  idx[base + 0] = (int)(b0 & 0xFFFll);
  idx[base + 1] = (int)(b1 & 0xFFFll);
  idx[base + 2] = (int)(b2 & 0xFFFll);
}

// ---------------------------------------------------------------------------
// K2: Z[b, s, o] = sum_c Ws[o, c] * sparse_data[b, c, s]   (o-contiguous!)
// ---------------------------------------------------------------------------
__global__ __launch_bounds__(256) void zproj_kernel(
    const float* __restrict__ sdata, const float* __restrict__ cw,
    float* __restrict__ Z) {
  const int b = blockIdx.y;
  const int s = blockIdx.x * 64 + (threadIdx.x & 63);
  const int rg = __builtin_amdgcn_readfirstlane(threadIdx.x >> 6);
  const float* __restrict__ xp = sdata + b * CS * S + s;
  const float* __restrict__ wp = cw + rg * 32 * CIN + CD;  // Ws columns

  float acc[32];
  #pragma unroll
  for (int i = 0; i < 32; ++i) acc[i] = 0.f;

  #pragma unroll 4
  for (int c = 0; c < CS; ++c) {
    const float xv = xp[c * S];  // coalesced across the wave
    #pragma unroll
    for (int i = 0; i < 32; ++i)
      acc[i] = fmaf(wp[i * CIN + c], xv, acc[i]);  // wave-uniform -> s_load
  }

  float4* zp = reinterpret_cast<float4*>(Z + (b * S + s) * CO + rg * 32);
  #pragma unroll
  for (int i = 0; i < 8; ++i)
    zp[i] = make_float4(acc[4*i+0], acc[4*i+1], acc[4*i+2], acc[4*i+3]);
}

// ---------------------------------------------------------------------------
// K3: y[b, o, n] = sum_c Wd[o,c]*dense_data[b,c,n] + sum_k w_k * Z[b,idx_k,o]
// + fused per-channel sum/sumsq (wave shuffle-reduce -> atomics).
// ---------------------------------------------------------------------------
__global__ __launch_bounds__(256) void ygemm_kernel(
    const float* __restrict__ ddata, const float* __restrict__ cw,
    const float* __restrict__ Z, const float* __restrict__ wgt,
    const int* __restrict__ idx, float* __restrict__ y,
    float* __restrict__ stats) {
  const int b = blockIdx.y;
  const int n = blockIdx.x * 64 + (threadIdx.x & 63);
  const int rg = __builtin_amdgcn_readfirstlane(threadIdx.x >> 6);
  const int lane = threadIdx.x & 63;
  const float* __restrict__ xp = ddata + b * CD * N + n;
  const float* __restrict__ wp = cw + rg * 32 * CIN;  // Wd columns

  float acc[32];
  #pragma unroll
  for (int i = 0; i < 32; ++i) acc[i] = 0.f;

  #pragma unroll 4
  for (int c = 0; c < CD; ++c) {
    const float xv = xp[c * N];
    #pragma unroll
    for (int i = 0; i < 32; ++i)
      acc[i] = fmaf(wp[i * CIN + c], xv, acc[i]);
  }

  const int pb = (b * N + n) * 3;
  #pragma unroll
  for (int k = 0; k < 3; ++k) {
    const float wk = wgt[pb + k];
    const int ik = idx[pb + k];
    const float4* zp =
        reinterpret_cast<const float4*>(Z + (b * S + ik) * CO + rg * 32);
    #pragma unroll
    for (int i = 0; i < 8; ++i) {
      float4 zv = zp[i];
      acc[4*i+0] = fmaf(wk, zv.x, acc[4*i+0]);
      acc[4*i+1] = fmaf(wk, zv.y, acc[4*i+1]);
      acc[4*i+2] = fmaf(wk, zv.z, acc[4*i+2]);
      acc[4*i+3] = fmaf(wk, zv.w, acc[4*i+3]);
    }
  }

  float* yp = y + b * CO * N + (rg * 32) * N + n;
  #pragma unroll
  for (int i = 0; i < 32; ++i) yp[i * N] = acc[i];

  // Fused BN batch-stats: wave-reduce each channel's sum / sumsq over the 64
  // n-lanes, then one atomic pair per (wave, channel).
  #pragma unroll
  for (int i = 0; i < 32; ++i) {
    float s = acc[i];
    float q = acc[i] * acc[i];
    #pragma unroll
    for (int m = 32; m > 0; m >>= 1) {
      s += __shfl_xor(s, m, 64);
      q += __shfl_xor(q, m, 64);
    }
    if (lane == 0) {
      atomicAdd(&stats[rg * 32 + i], s);
      atomicAdd(&stats[CO + rg * 32 + i], q);
    }
  }
}

// ---------------------------------------------------------------------------
// K4b: fold BN stats into per-channel scale/shift.
// ---------------------------------------------------------------------------
__global__ void scaleshift_kernel(const float* __restrict__ stats,
                                  const float* __restrict__ gamma,
                                  const float* __restrict__ beta,
                                  float* __restrict__ ss) {
  const int o = threadIdx.x;  // 128 threads
  const float invc = 1.f / (float)(B * N);
  const float m = stats[o] * invc;
  float v = stats[CO + o] * invc - m * m;
  v = fmaxf(v, 0.f);
  const float sc = gamma[o] / sqrtf(v + 1e-5f);
  ss[o] = sc;
  ss[CO + o] = beta[o] - m * sc;
}

// ---------------------------------------------------------------------------
// K5: in-place normalize + LeakyReLU(0.2) on d_out's y region (float4).
// ---------------------------------------------------------------------------
__global__ __launch_bounds__(256) void norm_kernel(float* __restrict__ y,
                                                   const float* __restrict__ ss) {
  const int i = blockIdx.x * 256 + threadIdx.x;  // float4 index
  const int o = (i >> 12) & (CO - 1);            // N/4 = 4096 float4 per (b,o)
  const float sc = ss[o];
  const float sh = ss[CO + o];
  float4* yp = reinterpret_cast<float4*>(y);
  float4 v = yp[i];
  float t;
  t = fmaf(v.x, sc, sh); v.x = fmaxf(t, 0.2f * t);
  t = fmaf(v.y, sc, sh); v.y = fmaxf(t, 0.2f * t);
  t = fmaf(v.z, sc, sh); v.z = fmaxf(t, 0.2f * t);
  t = fmaf(v.w, sc, sh); v.w = fmaxf(t, 0.2f * t);
  yp[i] = v;
}

// ---------------------------------------------------------------------------
extern "C" void kernel_launch(void* const* d_in, const int* in_sizes, int n_in,
                              void* d_out, int out_size, void* d_ws, size_t ws_size,
                              hipStream_t stream) {
  const float* dxyz  = (const float*)d_in[0];
  const float* sxyz  = (const float*)d_in[1];
  const float* ddata = (const float*)d_in[2];
  const float* sdata = (const float*)d_in[3];
  const float* cw    = (const float*)d_in[4];
  const float* gamma = (const float*)d_in[5];
  const float* beta  = (const float*)d_in[6];
  float* out = (float*)d_out;

  char* wsb = (char*)d_ws;
  // Layout (total 14,157,824 B — same proven footprint as last round):
  float*  wgt  = (float*) (wsb);                 // B*N*3 f32   =   786,432 B
  int*    idx  = (int*)   (wsb + 786432);        // B*N*3 i32   =   786,432 B
  double* ckey = (double*)(wsb + 1572864);       // NC*B*N*3 f64 = 12,582,912 B
  float*  Z    = (float*) (wsb + 1572864);       // B*S*CO f32 (aliases dead ckey)
  float*  stats= (float*) (wsb + 14155776);      // 256 f32
  float*  ss   = (float*) (wsb + 14156800);      // 256 f32

  hipMemsetAsync(stats, 0, 2 * CO * sizeof(float), stream);

  knn_chunk_kernel<<<dim3(N / (256 * P), NC, B), 256, 0, stream>>>(dxyz, sxyz, ckey);
  knn_merge_kernel<<<dim3(B * N / 256), 256, 0, stream>>>(ckey, wgt, idx);
  zproj_kernel<<<dim3(S / 64,  B), 256, 0, stream>>>(sdata, cw, Z);
  ygemm_kernel<<<dim3(N / 64,  B), 256, 0, stream>>>(ddata, cw, Z, wgt, idx, out, stats);
  scaleshift_kernel<<<1, 128, 0, stream>>>(stats, gamma, beta, ss);
  norm_kernel <<<(B * CO * N / 4) / 256, 256, 0, stream>>>(out, ss);

  hipMemcpyAsync(out + (size_t)B * CO * N, dxyz, (size_t)B * 3 * N * sizeof(float),
                 hipMemcpyDeviceToDevice, stream);
}

// Round 4
// 312.289 us; speedup vs baseline: 2.1855x; 2.1855x over previous
//
#include <hip/hip_runtime.h>

// Problem constants (fixed shapes from setup_inputs)
constexpr int B  = 4;
constexpr int N  = 16384;   // dense points
constexpr int S  = 4096;    // sparse points
constexpr int CD = 128;     // dense feature channels
constexpr int CS = 256;     // sparse feature channels
constexpr int CO = 128;     // output channels
constexpr int CIN = CD + CS; // 384

// KNN decomposition
constexpr int NC = 8;      // S-chunks
constexpr int CH = S / NC; // 512 sparse points per chunk
constexpr int P  = 2;      // dense points per thread -> 1024 blocks

// Packed key: f64(dist_f32) with sparse index OR'd into low 12 mantissa bits.
// Exact lexicographic (dist, idx) ordering: f32 dists differ by >= 2^-24 rel,
// idx bits perturb <= 2^-40 rel. Ties -> lower idx = jax top_k stability.
__device__ __forceinline__ double pack_key(float dist, unsigned sg) {
  return __longlong_as_double(
      (long long)(__double_as_longlong((double)dist) | (unsigned long long)sg));
}

// Insert x into ascending (k0,k1,k2), dropping the largest. 5 f64 min/max.
__device__ __forceinline__ void insert3(double& k0, double& k1, double& k2,
                                        double x) {
  const double m0 = fmax(k0, x);
  const double m1 = fmax(k1, x);
  k0 = fmin(k0, x);
  k1 = fmin(k1, m0);
  k2 = fmin(k2, m1);
}

// ---------------------------------------------------------------------------
// K1a: per-chunk top-3 as packed f64 keys. Pure min/max dataflow (no cmp /
// cndmask chains), LDS-broadcast sparse coords, 2 points per thread.
// ---------------------------------------------------------------------------
__global__ __launch_bounds__(256) void knn_chunk_kernel(
    const float* __restrict__ dxyz, const float* __restrict__ sxyz,
    double* __restrict__ ckey) {
  __shared__ float4 sp[CH];
  const int b = blockIdx.z;
  const int c = blockIdx.y;
  const int nbase = blockIdx.x * (256 * P);
  const int t = threadIdx.x;

  const float* sb = sxyz + b * 3 * S + c * CH;
  for (int j = t; j < CH; j += 256)
    sp[j] = make_float4(sb[j], sb[S + j], sb[2 * S + j], 0.f);
  __syncthreads();

  float bx[P], by[P], bz[P];
  double k0[P], k1[P], k2[P];
  #pragma unroll
  for (int p = 0; p < P; ++p) {
    const int n = nbase + p * 256 + t;
    bx[p] = dxyz[b * 3 * N + n];
    by[p] = dxyz[b * 3 * N + N + n];
    bz[p] = dxyz[b * 3 * N + 2 * N + n];
    k0[p] = k1[p] = k2[p] = 1e300;
  }

  #pragma unroll 4
  for (int j = 0; j < CH; ++j) {
    const float4 q = sp[j];                 // wave-uniform LDS broadcast
    const unsigned sg = (unsigned)(c * CH + j);  // global sparse index, 12 bits
    #pragma unroll
    for (int p = 0; p < P; ++p) {
      const float ex = bx[p] - q.x, ey = by[p] - q.y, ez = bz[p] - q.z;
      const float dist = fmaf(ex, ex, fmaf(ey, ey, ez * ez));
      insert3(k0[p], k1[p], k2[p], pack_key(dist, sg));
    }
  }

  #pragma unroll
  for (int p = 0; p < P; ++p) {
    const int n = nbase + p * 256 + t;
    const size_t base = (((size_t)c * B + b) * N + n) * 3;
    ckey[base + 0] = k0[p];
    ckey[base + 1] = k1[p];
    ckey[base + 2] = k2[p];
  }
}

// ---------------------------------------------------------------------------
// K1b: merge the NC per-chunk key triples, unpack, emit normalized weights.
// ---------------------------------------------------------------------------
__global__ __launch_bounds__(256) void knn_merge_kernel(
    const double* __restrict__ ckey, float* __restrict__ wgt,
    int* __restrict__ idx) {
  const int gid = blockIdx.x * 256 + threadIdx.x;  // = b*N + n
  double k0 = 1e300, k1 = 1e300, k2 = 1e300;
  #pragma unroll
  for (int c = 0; c < NC; ++c) {
    const size_t base = ((size_t)c * B * N + gid) * 3;
    insert3(k0, k1, k2, ckey[base + 0]);
    insert3(k0, k1, k2, ckey[base + 1]);
    insert3(k0, k1, k2, ckey[base + 2]);
  }
  const long long b0 = __double_as_longlong(k0);
  const long long b1 = __double_as_longlong(k1);
  const long long b2 = __double_as_longlong(k2);
  const float d0 = (float)__longlong_as_double(b0 & ~0xFFFll);
  const float d1 = (float)__longlong_as_double(b1 & ~0xFFFll);
  const float d2 = (float)__longlong_as_double(b2 & ~0xFFFll);
  const float w0 = 1.f / (d0 + 1e-8f);
  const float w1 = 1.f / (d1 + 1e-8f);
  const float w2 = 1.f / (d2 + 1e-8f);
  const float inv = 1.f / (w0 + w1 + w2);
  const size_t base = (size_t)gid * 3;
  wgt[base + 0] = w0 * inv;
  wgt[base + 1] = w1 * inv;
  wgt[base + 2] = w2 * inv;
  idx[base + 0] = (int)(b0 & 0xFFFll);
  idx[base + 1] = (int)(b1 & 0xFFFll);
  idx[base + 2] = (int)(b2 & 0xFFFll);
}

// ---------------------------------------------------------------------------
// K2: Z[b, s, o] = sum_c Ws[o, c] * sparse_data[b, c, s]   (o-contiguous!)
// ---------------------------------------------------------------------------
__global__ __launch_bounds__(256) void zproj_kernel(
    const float* __restrict__ sdata, const float* __restrict__ cw,
    float* __restrict__ Z) {
  const int b = blockIdx.y;
  const int s = blockIdx.x * 64 + (threadIdx.x & 63);
  const int rg = __builtin_amdgcn_readfirstlane(threadIdx.x >> 6);
  const float* __restrict__ xp = sdata + b * CS * S + s;
  const float* __restrict__ wp = cw + rg * 32 * CIN + CD;  // Ws columns

  float acc[32];
  #pragma unroll
  for (int i = 0; i < 32; ++i) acc[i] = 0.f;

  #pragma unroll 4
  for (int c = 0; c < CS; ++c) {
    const float xv = xp[c * S];  // coalesced across the wave
    #pragma unroll
    for (int i = 0; i < 32; ++i)
      acc[i] = fmaf(wp[i * CIN + c], xv, acc[i]);  // wave-uniform -> s_load
  }

  float4* zp = reinterpret_cast<float4*>(Z + (b * S + s) * CO + rg * 32);
  #pragma unroll
  for (int i = 0; i < 8; ++i)
    zp[i] = make_float4(acc[4*i+0], acc[4*i+1], acc[4*i+2], acc[4*i+3]);
}

// ---------------------------------------------------------------------------
// K3: y[b, o, n] = sum_c Wd[o,c]*dense_data[b,c,n] + sum_k w_k * Z[b,idx_k,o]
// (no fused stats — R3 showed the shuffle/atomic fusion forces an
//  accumulator spill: VGPR 36, VALUBusy 8%, 4.7x slowdown)
// ---------------------------------------------------------------------------
__global__ __launch_bounds__(256) void ygemm_kernel(
    const float* __restrict__ ddata, const float* __restrict__ cw,
    const float* __restrict__ Z, const float* __restrict__ wgt,
    const int* __restrict__ idx, float* __restrict__ y) {
  const int b = blockIdx.y;
  const int n = blockIdx.x * 64 + (threadIdx.x & 63);
  const int rg = __builtin_amdgcn_readfirstlane(threadIdx.x >> 6);
  const float* __restrict__ xp = ddata + b * CD * N + n;
  const float* __restrict__ wp = cw + rg * 32 * CIN;  // Wd columns

  float acc[32];
  #pragma unroll
  for (int i = 0; i < 32; ++i) acc[i] = 0.f;

  #pragma unroll 4
  for (int c = 0; c < CD; ++c) {
    const float xv = xp[c * N];
    #pragma unroll
    for (int i = 0; i < 32; ++i)
      acc[i] = fmaf(wp[i * CIN + c], xv, acc[i]);
  }

  const int pb = (b * N + n) * 3;
  #pragma unroll
  for (int k = 0; k < 3; ++k) {
    const float wk = wgt[pb + k];
    const int ik = idx[pb + k];
    const float4* zp =
        reinterpret_cast<const float4*>(Z + (b * S + ik) * CO + rg * 32);
    #pragma unroll
    for (int i = 0; i < 8; ++i) {
      float4 zv = zp[i];
      acc[4*i+0] = fmaf(wk, zv.x, acc[4*i+0]);
      acc[4*i+1] = fmaf(wk, zv.y, acc[4*i+1]);
      acc[4*i+2] = fmaf(wk, zv.z, acc[4*i+2]);
      acc[4*i+3] = fmaf(wk, zv.w, acc[4*i+3]);
    }
  }

  float* yp = y + b * CO * N + (rg * 32) * N + n;
  #pragma unroll
  for (int i = 0; i < 32; ++i) yp[i * N] = acc[i];
}

// ---------------------------------------------------------------------------
// K4: per-channel sum / sumsq over (B, N).
// ---------------------------------------------------------------------------
__global__ __launch_bounds__(256) void stats_kernel(
    const float* __restrict__ y, float* __restrict__ stats) {
  const int o = blockIdx.x;
  const int b = blockIdx.y;
  const float4* yp = reinterpret_cast<const float4*>(y + (b * CO + o) * N);
  float s = 0.f, sq = 0.f;
  for (int j = threadIdx.x; j < N / 4; j += 256) {
    float4 v = yp[j];
    s  += v.x + v.y + v.z + v.w;
    sq += v.x * v.x + v.y * v.y + v.z * v.z + v.w * v.w;
  }
  __shared__ float ls[256];
  __shared__ float lq[256];
  ls[threadIdx.x] = s;
  lq[threadIdx.x] = sq;
  __syncthreads();
  for (int st = 128; st > 0; st >>= 1) {
    if (threadIdx.x < (unsigned)st) {
      ls[threadIdx.x] += ls[threadIdx.x + st];
      lq[threadIdx.x] += lq[threadIdx.x + st];
    }
    __syncthreads();
  }
  if (threadIdx.x == 0) {
    atomicAdd(&stats[o], ls[0]);
    atomicAdd(&stats[CO + o], lq[0]);
  }
}

// ---------------------------------------------------------------------------
// K4b: fold BN stats into per-channel scale/shift.
// ---------------------------------------------------------------------------
__global__ void scaleshift_kernel(const float* __restrict__ stats,
                                  const float* __restrict__ gamma,
                                  const float* __restrict__ beta,
                                  float* __restrict__ ss) {
  const int o = threadIdx.x;  // 128 threads
  const float invc = 1.f / (float)(B * N);
  const float m = stats[o] * invc;
  float v = stats[CO + o] * invc - m * m;
  v = fmaxf(v, 0.f);
  const float sc = gamma[o] / sqrtf(v + 1e-5f);
  ss[o] = sc;
  ss[CO + o] = beta[o] - m * sc;
}

// ---------------------------------------------------------------------------
// K5: in-place normalize + LeakyReLU(0.2) on d_out's y region (float4).
// ---------------------------------------------------------------------------
__global__ __launch_bounds__(256) void norm_kernel(float* __restrict__ y,
                                                   const float* __restrict__ ss) {
  const int i = blockIdx.x * 256 + threadIdx.x;  // float4 index
  const int o = (i >> 12) & (CO - 1);            // N/4 = 4096 float4 per (b,o)
  const float sc = ss[o];
  const float sh = ss[CO + o];
  float4* yp = reinterpret_cast<float4*>(y);
  float4 v = yp[i];
  float t;
  t = fmaf(v.x, sc, sh); v.x = fmaxf(t, 0.2f * t);
  t = fmaf(v.y, sc, sh); v.y = fmaxf(t, 0.2f * t);
  t = fmaf(v.z, sc, sh); v.z = fmaxf(t, 0.2f * t);
  t = fmaf(v.w, sc, sh); v.w = fmaxf(t, 0.2f * t);
  yp[i] = v;
}

// ---------------------------------------------------------------------------
extern "C" void kernel_launch(void* const* d_in, const int* in_sizes, int n_in,
                              void* d_out, int out_size, void* d_ws, size_t ws_size,
                              hipStream_t stream) {
  const float* dxyz  = (const float*)d_in[0];
  const float* sxyz  = (const float*)d_in[1];
  const float* ddata = (const float*)d_in[2];
  const float* sdata = (const float*)d_in[3];
  const float* cw    = (const float*)d_in[4];
  const float* gamma = (const float*)d_in[5];
  const float* beta  = (const float*)d_in[6];
  float* out = (float*)d_out;

  char* wsb = (char*)d_ws;
  // Layout (total 14,157,824 B):
  float*  wgt  = (float*) (wsb);                 // B*N*3 f32   =   786,432 B
  int*    idx  = (int*)   (wsb + 786432);        // B*N*3 i32   =   786,432 B
  double* ckey = (double*)(wsb + 1572864);       // NC*B*N*3 f64 = 12,582,912 B
  float*  Z    = (float*) (wsb + 1572864);       // B*S*CO f32 (aliases dead ckey)
  float*  stats= (float*) (wsb + 14155776);      // 256 f32
  float*  ss   = (float*) (wsb + 14156800);      // 256 f32

  hipMemsetAsync(stats, 0, 2 * CO * sizeof(float), stream);

  knn_chunk_kernel<<<dim3(N / (256 * P), NC, B), 256, 0, stream>>>(dxyz, sxyz, ckey);
  knn_merge_kernel<<<dim3(B * N / 256), 256, 0, stream>>>(ckey, wgt, idx);
  zproj_kernel<<<dim3(S / 64,  B), 256, 0, stream>>>(sdata, cw, Z);
  ygemm_kernel<<<dim3(N / 64,  B), 256, 0, stream>>>(ddata, cw, Z, wgt, idx, out);
  stats_kernel<<<dim3(CO, B), 256, 0, stream>>>(out, stats);
  scaleshift_kernel<<<1, 128, 0, stream>>>(stats, gamma, beta, ss);
  norm_kernel <<<(B * CO * N / 4) / 256, 256, 0, stream>>>(out, ss);

  hipMemcpyAsync(out + (size_t)B * CO * N, dxyz, (size_t)B * 3 * N * sizeof(float),
                 hipMemcpyDeviceToDevice, stream);
}

// Round 5
// 243.231 us; speedup vs baseline: 2.8060x; 1.2839x over previous
//
#include <hip/hip_runtime.h>

// Problem constants (fixed shapes from setup_inputs)
constexpr int B  = 4;
constexpr int N  = 16384;   // dense points
constexpr int S  = 4096;    // sparse points
constexpr int CD = 128;     // dense feature channels
constexpr int CS = 256;     // sparse feature channels
constexpr int CO = 128;     // output channels
constexpr int CIN = CD + CS; // 384

// KNN decomposition
constexpr int NC = 8;      // S-chunks
constexpr int CH = S / NC; // 512 sparse points per chunk
constexpr int P  = 2;      // dense points per thread -> 1024 blocks

// Packed key: f64(dist_f32) with sparse index OR'd into low 12 mantissa bits.
// Exact lexicographic (dist, idx) ordering: f32 dists differ by >= 2^-24 rel,
// idx bits perturb <= 2^-40 rel. Ties -> lower idx = jax top_k stability.
__device__ __forceinline__ double pack_key(float dist, unsigned sg) {
  return __longlong_as_double(
      (long long)(__double_as_longlong((double)dist) | (unsigned long long)sg));
}

// Insert x into ascending (k0,k1,k2), dropping the largest. 5 f64 min/max.
__device__ __forceinline__ void insert3(double& k0, double& k1, double& k2,
                                        double x) {
  const double m0 = fmax(k0, x);
  const double m1 = fmax(k1, x);
  k0 = fmin(k0, x);
  k1 = fmin(k1, m0);
  k2 = fmin(k2, m1);
}

// ---------------------------------------------------------------------------
// K1a: per-chunk top-3 as packed f64 keys. Pure min/max dataflow (no cmp /
// cndmask chains), LDS-broadcast sparse coords, 2 points per thread.
// (VALU-issue-bound at ~100% busy — leave as-is this round.)
// ---------------------------------------------------------------------------
__global__ __launch_bounds__(256) void knn_chunk_kernel(
    const float* __restrict__ dxyz, const float* __restrict__ sxyz,
    double* __restrict__ ckey) {
  __shared__ float4 sp[CH];
  const int b = blockIdx.z;
  const int c = blockIdx.y;
  const int nbase = blockIdx.x * (256 * P);
  const int t = threadIdx.x;

  const float* sb = sxyz + b * 3 * S + c * CH;
  for (int j = t; j < CH; j += 256)
    sp[j] = make_float4(sb[j], sb[S + j], sb[2 * S + j], 0.f);
  __syncthreads();

  float bx[P], by[P], bz[P];
  double k0[P], k1[P], k2[P];
  #pragma unroll
  for (int p = 0; p < P; ++p) {
    const int n = nbase + p * 256 + t;
    bx[p] = dxyz[b * 3 * N + n];
    by[p] = dxyz[b * 3 * N + N + n];
    bz[p] = dxyz[b * 3 * N + 2 * N + n];
    k0[p] = k1[p] = k2[p] = 1e300;
  }

  #pragma unroll 4
  for (int j = 0; j < CH; ++j) {
    const float4 q = sp[j];                 // wave-uniform LDS broadcast
    const unsigned sg = (unsigned)(c * CH + j);  // global sparse index, 12 bits
    #pragma unroll
    for (int p = 0; p < P; ++p) {
      const float ex = bx[p] - q.x, ey = by[p] - q.y, ez = bz[p] - q.z;
      const float dist = fmaf(ex, ex, fmaf(ey, ey, ez * ez));
      insert3(k0[p], k1[p], k2[p], pack_key(dist, sg));
    }
  }

  #pragma unroll
  for (int p = 0; p < P; ++p) {
    const int n = nbase + p * 256 + t;
    const size_t base = (((size_t)c * B + b) * N + n) * 3;
    ckey[base + 0] = k0[p];
    ckey[base + 1] = k1[p];
    ckey[base + 2] = k2[p];
  }
}

// ---------------------------------------------------------------------------
// K1b: merge the NC per-chunk key triples, unpack, emit normalized weights.
// ---------------------------------------------------------------------------
__global__ __launch_bounds__(256) void knn_merge_kernel(
    const double* __restrict__ ckey, float* __restrict__ wgt,
    int* __restrict__ idx) {
  const int gid = blockIdx.x * 256 + threadIdx.x;  // = b*N + n
  double k0 = 1e300, k1 = 1e300, k2 = 1e300;
  #pragma unroll
  for (int c = 0; c < NC; ++c) {
    const size_t base = ((size_t)c * B * N + gid) * 3;
    insert3(k0, k1, k2, ckey[base + 0]);
    insert3(k0, k1, k2, ckey[base + 1]);
    insert3(k0, k1, k2, ckey[base + 2]);
  }
  const long long b0 = __double_as_longlong(k0);
  const long long b1 = __double_as_longlong(k1);
  const long long b2 = __double_as_longlong(k2);
  const float d0 = (float)__longlong_as_double(b0 & ~0xFFFll);
  const float d1 = (float)__longlong_as_double(b1 & ~0xFFFll);
  const float d2 = (float)__longlong_as_double(b2 & ~0xFFFll);
  const float w0 = 1.f / (d0 + 1e-8f);
  const float w1 = 1.f / (d1 + 1e-8f);
  const float w2 = 1.f / (d2 + 1e-8f);
  const float inv = 1.f / (w0 + w1 + w2);
  const size_t base = (size_t)gid * 3;
  wgt[base + 0] = w0 * inv;
  wgt[base + 1] = w1 * inv;
  wgt[base + 2] = w2 * inv;
  idx[base + 0] = (int)(b0 & 0xFFFll);
  idx[base + 1] = (int)(b1 & 0xFFFll);
  idx[base + 2] = (int)(b2 & 0xFFFll);
}

// ---------------------------------------------------------------------------
// K1c: transpose conv_w -> Wt[c][o] (o contiguous) so zproj's per-c weight
// fetch is one contiguous s_load_dwordx16. Tiny (49K elements).
// ---------------------------------------------------------------------------
__global__ __launch_bounds__(256) void wtrans_kernel(
    const float* __restrict__ cw, float* __restrict__ wt) {
  const int i = blockIdx.x * 256 + threadIdx.x;  // over CO*CIN, coalesced read
  const int o = i / CIN;
  const int c = i - o * CIN;
  wt[c * CO + o] = cw[i];
}

// ---------------------------------------------------------------------------
// K2: Z[b, s, o] = sum_c Ws[o, c] * sparse_data[b, c, s]   (o-contiguous!)
// v2: 1-wave blocks, 16 channels/thread, grid (S/64, CO/16, B) = 2048 waves
// (2/SIMD). Per c-iter: 1 coalesced xv load + 1 contiguous s_loadx16 + 16 fma.
// R4's version was latency-dead: 1 wave/SIMD, VGPR 24, VALUBusy 12%.
// ---------------------------------------------------------------------------
__global__ __launch_bounds__(64) void zproj_kernel(
    const float* __restrict__ sdata, const float* __restrict__ wt,
    float* __restrict__ Z) {
  const int b = blockIdx.z;
  const int og = blockIdx.y;                      // 8 groups of 16 channels
  const int s = blockIdx.x * 64 + threadIdx.x;
  const float* __restrict__ xp = sdata + b * CS * S + s;
  const float* __restrict__ wp = wt + CD * CO + og * 16;  // Wt[CD+c][og*16..]

  float acc[16];
  #pragma unroll
  for (int i = 0; i < 16; ++i) acc[i] = 0.f;

  #pragma unroll 4
  for (int c = 0; c < CS; ++c) {
    const float xv = xp[c * S];        // coalesced across the wave
    #pragma unroll
    for (int i = 0; i < 16; ++i)
      acc[i] = fmaf(wp[c * CO + i], xv, acc[i]);  // uniform 64B s_load
  }

  float4* zp = reinterpret_cast<float4*>(Z + (b * S + s) * CO + og * 16);
  #pragma unroll
  for (int i = 0; i < 4; ++i)
    zp[i] = make_float4(acc[4*i+0], acc[4*i+1], acc[4*i+2], acc[4*i+3]);
}

// ---------------------------------------------------------------------------
// K3: y[b, o, n] = sum_c Wd[o,c]*dense_data[b,c,n] + sum_k w_k * Z[b,idx_k,o]
// (no fused stats — R3 showed that fusion forces an accumulator spill)
// ---------------------------------------------------------------------------
__global__ __launch_bounds__(256) void ygemm_kernel(
    const float* __restrict__ ddata, const float* __restrict__ cw,
    const float* __restrict__ Z, const float* __restrict__ wgt,
    const int* __restrict__ idx, float* __restrict__ y) {
  const int b = blockIdx.y;
  const int n = blockIdx.x * 64 + (threadIdx.x & 63);
  const int rg = __builtin_amdgcn_readfirstlane(threadIdx.x >> 6);
  const float* __restrict__ xp = ddata + b * CD * N + n;
  const float* __restrict__ wp = cw + rg * 32 * CIN;  // Wd columns

  float acc[32];
  #pragma unroll
  for (int i = 0; i < 32; ++i) acc[i] = 0.f;

  #pragma unroll 4
  for (int c = 0; c < CD; ++c) {
    const float xv = xp[c * N];
    #pragma unroll
    for (int i = 0; i < 32; ++i)
      acc[i] = fmaf(wp[i * CIN + c], xv, acc[i]);
  }

  const int pb = (b * N + n) * 3;
  #pragma unroll
  for (int k = 0; k < 3; ++k) {
    const float wk = wgt[pb + k];
    const int ik = idx[pb + k];
    const float4* zp =
        reinterpret_cast<const float4*>(Z + (b * S + ik) * CO + rg * 32);
    #pragma unroll
    for (int i = 0; i < 8; ++i) {
      float4 zv = zp[i];
      acc[4*i+0] = fmaf(wk, zv.x, acc[4*i+0]);
      acc[4*i+1] = fmaf(wk, zv.y, acc[4*i+1]);
      acc[4*i+2] = fmaf(wk, zv.z, acc[4*i+2]);
      acc[4*i+3] = fmaf(wk, zv.w, acc[4*i+3]);
    }
  }

  float* yp = y + b * CO * N + (rg * 32) * N + n;
  #pragma unroll
  for (int i = 0; i < 32; ++i) yp[i * N] = acc[i];
}

// ---------------------------------------------------------------------------
// K4: per-channel sum / sumsq over (B, N).
// ---------------------------------------------------------------------------
__global__ __launch_bounds__(256) void stats_kernel(
    const float* __restrict__ y, float* __restrict__ stats) {
  const int o = blockIdx.x;
  const int b = blockIdx.y;
  const float4* yp = reinterpret_cast<const float4*>(y + (b * CO + o) * N);
  float s = 0.f, sq = 0.f;
  for (int j = threadIdx.x; j < N / 4; j += 256) {
    float4 v = yp[j];
    s  += v.x + v.y + v.z + v.w;
    sq += v.x * v.x + v.y * v.y + v.z * v.z + v.w * v.w;
  }
  __shared__ float ls[256];
  __shared__ float lq[256];
  ls[threadIdx.x] = s;
  lq[threadIdx.x] = sq;
  __syncthreads();
  for (int st = 128; st > 0; st >>= 1) {
    if (threadIdx.x < (unsigned)st) {
      ls[threadIdx.x] += ls[threadIdx.x + st];
      lq[threadIdx.x] += lq[threadIdx.x + st];
    }
    __syncthreads();
  }
  if (threadIdx.x == 0) {
    atomicAdd(&stats[o], ls[0]);
    atomicAdd(&stats[CO + o], lq[0]);
  }
}

// ---------------------------------------------------------------------------
// K4b: fold BN stats into per-channel scale/shift.
// ---------------------------------------------------------------------------
__global__ void scaleshift_kernel(const float* __restrict__ stats,
                                  const float* __restrict__ gamma,
                                  const float* __restrict__ beta,
                                  float* __restrict__ ss) {
  const int o = threadIdx.x;  // 128 threads
  const float invc = 1.f / (float)(B * N);
  const float m = stats[o] * invc;
  float v = stats[CO + o] * invc - m * m;
  v = fmaxf(v, 0.f);
  const float sc = gamma[o] / sqrtf(v + 1e-5f);
  ss[o] = sc;
  ss[CO + o] = beta[o] - m * sc;
}

// ---------------------------------------------------------------------------
// K5: in-place normalize + LeakyReLU(0.2) on d_out's y region (float4).
// ---------------------------------------------------------------------------
__global__ __launch_bounds__(256) void norm_kernel(float* __restrict__ y,
                                                   const float* __restrict__ ss) {
  const int i = blockIdx.x * 256 + threadIdx.x;  // float4 index
  const int o = (i >> 12) & (CO - 1);            // N/4 = 4096 float4 per (b,o)
  const float sc = ss[o];
  const float sh = ss[CO + o];
  float4* yp = reinterpret_cast<float4*>(y);
  float4 v = yp[i];
  float t;
  t = fmaf(v.x, sc, sh); v.x = fmaxf(t, 0.2f * t);
  t = fmaf(v.y, sc, sh); v.y = fmaxf(t, 0.2f * t);
  t = fmaf(v.z, sc, sh); v.z = fmaxf(t, 0.2f * t);
  t = fmaf(v.w, sc, sh); v.w = fmaxf(t, 0.2f * t);
  yp[i] = v;
}

// ---------------------------------------------------------------------------
extern "C" void kernel_launch(void* const* d_in, const int* in_sizes, int n_in,
                              void* d_out, int out_size, void* d_ws, size_t ws_size,
                              hipStream_t stream) {
  const float* dxyz  = (const float*)d_in[0];
  const float* sxyz  = (const float*)d_in[1];
  const float* ddata = (const float*)d_in[2];
  const float* sdata = (const float*)d_in[3];
  const float* cw    = (const float*)d_in[4];
  const float* gamma = (const float*)d_in[5];
  const float* beta  = (const float*)d_in[6];
  float* out = (float*)d_out;

  char* wsb = (char*)d_ws;
  // Layout (total 14,157,824 B — same proven footprint):
  float*  wgt  = (float*) (wsb);                 // B*N*3 f32   =   786,432 B
  int*    idx  = (int*)   (wsb + 786432);        // B*N*3 i32   =   786,432 B
  double* ckey = (double*)(wsb + 1572864);       // NC*B*N*3 f64 = 12,582,912 B
  // After knn_merge, ckey is dead; Z (8 MB) and Wt (192 KB) alias into it.
  float*  Z    = (float*) (wsb + 1572864);       // B*S*CO f32  = 8,388,608 B
  float*  wt   = (float*) (wsb + 9961472);       // CIN*CO f32  =   196,608 B
  float*  stats= (float*) (wsb + 14155776);      // 256 f32
  float*  ss   = (float*) (wsb + 14156800);      // 256 f32

  hipMemsetAsync(stats, 0, 2 * CO * sizeof(float), stream);

  knn_chunk_kernel<<<dim3(N / (256 * P), NC, B), 256, 0, stream>>>(dxyz, sxyz, ckey);
  knn_merge_kernel<<<dim3(B * N / 256), 256, 0, stream>>>(ckey, wgt, idx);
  wtrans_kernel   <<<dim3(CO * CIN / 256), 256, 0, stream>>>(cw, wt);
  zproj_kernel    <<<dim3(S / 64, CO / 16, B), 64, 0, stream>>>(sdata, wt, Z);
  ygemm_kernel    <<<dim3(N / 64, B), 256, 0, stream>>>(ddata, cw, Z, wgt, idx, out);
  stats_kernel    <<<dim3(CO, B), 256, 0, stream>>>(out, stats);
  scaleshift_kernel<<<1, 128, 0, stream>>>(stats, gamma, beta, ss);
  norm_kernel     <<<(B * CO * N / 4) / 256, 256, 0, stream>>>(out, ss);

  hipMemcpyAsync(out + (size_t)B * CO * N, dxyz, (size_t)B * 3 * N * sizeof(float),
                 hipMemcpyDeviceToDevice, stream);
}